// Round 3
// baseline (223.486 us; speedup 1.0000x reference)
//
#include <hip/hip_runtime.h>
#include <math.h>

// ---------------------------------------------------------------------------
// Fused MoE top-2 router, MI355X (gfx950) — round 3.
// R2 failed on latency: 105KB LDS -> 1 block/CU -> 1 wave/SIMD, and 176 live
// regs vs 152 alloc serialized ds_read->FMA chains. This round:
//  - 512 threads (8 waves = 2/SIMD): waves = (token-group tg in 4) x (k-half
//    kh in 2); every wave works on every chunk -> TLP covers LDS/HBM latency.
//  - x read straight from global (once, coalesced; 4-lane broadcast absorbed
//    by the coalescer) -> LDS holds only W: 2 x 32KB double buffer.
//  - lane = (eg in 4, ks in 16): acc[8 tok][16 exp], 0.5 B LDS / lane-FMA.
//  LDS pipe ~25us < FMA floor 27.3us -> compute-bound target ~33-40us.
// ---------------------------------------------------------------------------

#define NT 8192
#define ND 4096
#define NE 64
#define TB 32             // tokens per block
#define BK 128            // k per chunk
#define NCHUNK (ND / BK)  // 32

__device__ __forceinline__ void gload16(const float* g, float* l) {
    __builtin_amdgcn_global_load_lds(
        (const __attribute__((address_space(1))) void*)g,
        (__attribute__((address_space(3))) void*)l, 16, 0, 0);
}

__global__ __launch_bounds__(512, 1)
void router_main(const float* __restrict__ x, const float* __restrict__ W,
                 float* __restrict__ out, float* __restrict__ ws)
{
    __shared__ float wbuf[2][NE * BK];   // 2 x 32 KiB, W chunk double-buffer
    __shared__ float lg[TB][68];         // block logits, padded stride
    __shared__ float load_s[NE];

    const int tid  = threadIdx.x;
    const int wave = tid >> 6;
    const int lane = tid & 63;
    const int kh   = wave & 1;    // k-half within chunk (64 floats)
    const int tg   = wave >> 1;   // token octet 0..3
    const int eg   = lane >> 4;   // expert group (16 experts)
    const int ks   = lane & 15;   // k slice (4 floats)

    if (tid < NE) load_s[tid] = 0.f;

    const int tok0 = blockIdx.x * TB;

    float acc[8][16];
    #pragma unroll
    for (int t = 0; t < 8; t++)
        #pragma unroll
        for (int e = 0; e < 16; e++) acc[t][e] = 0.f;

    // prologue: stage W chunk 0 into buffer 0 (512 thr x 4 x 16B = 32KB)
    #pragma unroll
    for (int r = 0; r < 4; r++) {
        int f4 = r * 512 + tid;
        int e  = f4 >> 5;             // 32 float4 per expert row
        int kp = (f4 & 31) << 2;
        gload16(W + (size_t)e * ND + kp, &wbuf[0][f4 << 2]);
    }
    __syncthreads();

    const float* xbase = x + (size_t)(tok0 + tg * 8) * ND + kh * 64 + ks * 4;

    #pragma unroll 1
    for (int c = 0; c < NCHUNK; ++c) {
        const int b = c & 1;
        if (c + 1 < NCHUNK) {
            const int koff = (c + 1) * BK;
            #pragma unroll
            for (int r = 0; r < 4; r++) {
                int f4 = r * 512 + tid;
                int e  = f4 >> 5;
                int kp = (f4 & 31) << 2;
                gload16(W + (size_t)e * ND + koff + kp, &wbuf[b ^ 1][f4 << 2]);
            }
        }

        // x fragments straight from global (read-once; ks lanes cover 256B)
        float4 xv[8];
        #pragma unroll
        for (int t = 0; t < 8; t++)
            xv[t] = *reinterpret_cast<const float4*>(xbase + (size_t)t * ND + c * BK);

        const float* wb = &wbuf[b][(eg * 16) * BK + kh * 64 + ks * 4];
        #pragma unroll
        for (int es = 0; es < 4; es++) {
            float4 wv[4];
            #pragma unroll
            for (int e2 = 0; e2 < 4; e2++)
                wv[e2] = *reinterpret_cast<const float4*>(wb + (es * 4 + e2) * BK);
            #pragma unroll
            for (int t = 0; t < 8; t++) {
                #pragma unroll
                for (int e2 = 0; e2 < 4; e2++) {
                    float a = acc[t][es * 4 + e2];
                    a = fmaf(xv[t].x, wv[e2].x, a);
                    a = fmaf(xv[t].y, wv[e2].y, a);
                    a = fmaf(xv[t].z, wv[e2].z, a);
                    a = fmaf(xv[t].w, wv[e2].w, a);
                    acc[t][es * 4 + e2] = a;
                }
            }
        }
        __syncthreads();
    }

    // ---- k-slice butterfly over ks (lane bits 0..3) ----
    #pragma unroll
    for (int t = 0; t < 8; t++)
        #pragma unroll
        for (int e = 0; e < 16; e++) {
            float v = acc[t][e];
            v += __shfl_xor(v, 1);
            v += __shfl_xor(v, 2);
            v += __shfl_xor(v, 4);
            v += __shfl_xor(v, 8);
            acc[t][e] = v;
        }

    // kh=1 waves publish their half-k partials (lane ks==t writes token t)
    #pragma unroll
    for (int t = 0; t < 8; t++) {
        if (kh == 1 && ks == t) {
            #pragma unroll
            for (int e4 = 0; e4 < 4; e4++)
                *reinterpret_cast<float4*>(&lg[tg * 8 + t][eg * 16 + e4 * 4]) =
                    make_float4(acc[t][e4 * 4], acc[t][e4 * 4 + 1],
                                acc[t][e4 * 4 + 2], acc[t][e4 * 4 + 3]);
        }
    }
    __syncthreads();
    // kh=0 waves add their half and write the full logits
    #pragma unroll
    for (int t = 0; t < 8; t++) {
        if (kh == 0 && ks == t) {
            #pragma unroll
            for (int e4 = 0; e4 < 4; e4++) {
                float4 v = *reinterpret_cast<const float4*>(
                    &lg[tg * 8 + t][eg * 16 + e4 * 4]);
                v.x += acc[t][e4 * 4];
                v.y += acc[t][e4 * 4 + 1];
                v.z += acc[t][e4 * 4 + 2];
                v.w += acc[t][e4 * 4 + 3];
                *reinterpret_cast<float4*>(&lg[tg * 8 + t][eg * 16 + e4 * 4]) = v;
            }
        }
    }
    __syncthreads();

    // ---- epilogue: thread handles token (tid & 31), redundant across thrds
    const int t = tid & 31;
    float lgv[NE];
    #pragma unroll
    for (int e4 = 0; e4 < 16; e4++) {
        float4 v = *reinterpret_cast<const float4*>(&lg[t][e4 * 4]);
        lgv[e4 * 4]     = v.x;
        lgv[e4 * 4 + 1] = v.y;
        lgv[e4 * 4 + 2] = v.z;
        lgv[e4 * 4 + 3] = v.w;
    }

    float m = -3.0e38f;
    #pragma unroll
    for (int e = 0; e < NE; e++) m = fmaxf(m, lgv[e]);
    float se = 0.f;
    #pragma unroll
    for (int e = 0; e < NE; e++) se += __expf(lgv[e] - m);
    const float lse = m + __logf(se);
    const float inv = 1.f / se;

    float v1 = -3.0e38f, v2 = -3.0e38f;
    int   i1 = 0, i2 = 0;
    #pragma unroll
    for (int e = 0; e < NE; e++) {
        const float v = lgv[e];
        if (v > v1)      { v2 = v1; i2 = i1; v1 = v; i1 = e; }
        else if (v > v2) { v2 = v;  i2 = e; }
    }
    const float p1 = __expf(v1 - m) * inv;
    const float p2 = __expf(v2 - m) * inv;
    const float dn = fmaxf(p1 + p2, 1e-9f);

    float ssum = 0.f;
    #pragma unroll
    for (int e = 0; e < NE; e++) ssum += lgv[e];

    if (tid < TB) {
        const int tok = tok0 + t;
        out[2 * tok]              = (float)i1;
        out[2 * tok + 1]          = (float)i2;
        out[2 * NT + 2 * tok]     = p1 / dn;
        out[2 * NT + 2 * tok + 1] = p2 / dn;
        atomicAdd(&load_s[i1], 1.0f);
    }

    // wave 0 (tid<64 covers each token exactly twice -> 0.5 weight)
    if (tid < 64) {
        float zv = lse * lse, sv = ssum;
        #pragma unroll
        for (int mk = 1; mk < 64; mk <<= 1) {
            zv += __shfl_xor(zv, mk);
            sv += __shfl_xor(sv, mk);
        }
        if (tid == 0) {
            atomicAdd(&ws[128], 0.5f * zv);
            atomicAdd(&ws[129], 0.5f * sv);
        }
        #pragma unroll
        for (int e = 0; e < NE; e++) {
            float v = __expf(lgv[e] - m) * inv;
            #pragma unroll
            for (int mk = 1; mk < 64; mk <<= 1) v += __shfl_xor(v, mk);
            if (tid == e) atomicAdd(&ws[e], 0.5f * v);   // importance[e]
        }
    }

    __syncthreads();
    if (tid < NE) atomicAdd(&ws[NE + tid], load_s[tid]);
}

__global__ void finalize(const float* __restrict__ ws, float* __restrict__ out)
{
    const int l = threadIdx.x;   // one wave
    const float imp = ws[l];
    const float ld  = ws[NE + l];
    float is = imp, ls = ld;
    #pragma unroll
    for (int mk = 1; mk < 64; mk <<= 1) { is += __shfl_xor(is, mk); ls += __shfl_xor(ls, mk); }
    float v = (imp / fmaxf(is, 1e-9f)) * (ld / fmaxf(ls, 1e-9f));
    #pragma unroll
    for (int mk = 1; mk < 64; mk <<= 1) v += __shfl_xor(v, mk);
    if (l == 0) {
        out[4 * NT]     = (ws[128] / (float)NT) * 0.001f;        // router_z_loss
        out[4 * NT + 1] = v * (float)(NE * NE) * 0.01f;          // load_balance_loss
        out[4 * NT + 2] = ws[129] / (float)((size_t)NT * NE);    // logits_mean
    }
}

extern "C" void kernel_launch(void* const* d_in, const int* in_sizes, int n_in,
                              void* d_out, int out_size, void* d_ws, size_t ws_size,
                              hipStream_t stream) {
    const float* x = (const float*)d_in[0];
    const float* W = (const float*)d_in[1];
    float* out = (float*)d_out;
    float* ws  = (float*)d_ws;

    hipMemsetAsync(ws, 0, 130 * sizeof(float), stream);
    hipLaunchKernelGGL(router_main, dim3(NT / TB), dim3(512), 0, stream, x, W, out, ws);
    hipLaunchKernelGGL(finalize, dim3(1), dim3(64), 0, stream, ws, out);
}